// Round 8
// baseline (152.157 us; speedup 1.0000x reference)
//
#include <hip/hip_runtime.h>
#include <hip/hip_bf16.h>

// Problem constants
#define BB 16
#define TT 2048
#define CC 128
#define HH 128
#define NQT128 16          // q tiles of 128 rows

typedef __bf16 bf16x8 __attribute__((ext_vector_type(8)));
typedef float  f32x4  __attribute__((ext_vector_type(4)));
typedef unsigned long long u64;

// ws layout (bf16 elems unless noted):
//   Qs  [b][tt16 128][ks 4][lane 64][j 8]   (exp2-domain scale folded)
//   Ks  [b][tt16 128][ks 4][lane 64][j 8]   (one 64-key tile = 16 KB contig)
//   Vs  [b][t32 64][h16 8][lane 64][j 8]    (one 64-key tile = 16 KB contig)
//   Wbf 3*128*128  (Wq pre-scaled)
//   partial slots: bf16 o[128*128] (32768 B) + float l[128] (512 B)
#define BTH       ((size_t)BB * TT * HH)
#define WBF_OFF   (3 * BTH)
#define PARTIAL_OFF_BYTES (3 * BTH * 2 + 3 * 128 * 128 * 2)
#define SLOT_BYTES 33280
#define SLOT_L_OFF 32768

static __device__ __forceinline__ bf16x8 load_cvt8(const float* __restrict__ p) {
    float4 a = *(const float4*)p;
    float4 b = *(const float4*)(p + 4);
    bf16x8 r;
    r[0] = (__bf16)a.x; r[1] = (__bf16)a.y; r[2] = (__bf16)a.z; r[3] = (__bf16)a.w;
    r[4] = (__bf16)b.x; r[5] = (__bf16)b.y; r[6] = (__bf16)b.z; r[7] = (__bf16)b.w;
    return r;
}

// async global->LDS, 16 B/lane: data lands at lds_base + lane*16
static __device__ __forceinline__ void load_lds16(const void* g, void* l) {
    __builtin_amdgcn_global_load_lds(
        (const __attribute__((address_space(1))) unsigned int*)g,
        (__attribute__((address_space(3))) unsigned int*)l, 16, 0, 0);
}

// ---------------------------------------------------------------------------
// W pre-convert: fp32 -> bf16, Wq scaled by C^-0.5 * log2e.
// ---------------------------------------------------------------------------
__global__ __launch_bounds__(256) void wcvt_kernel(
    const float* __restrict__ Wq, const float* __restrict__ Wk,
    const float* __restrict__ Wv, __bf16* __restrict__ wbf)
{
    int idx = blockIdx.x * 256 + threadIdx.x;          // < 49152
    int m = idx >> 14;
    int e = idx & 16383;
    const float* src = (m == 0) ? Wq : (m == 1) ? Wk : Wv;
    float sc = (m == 0) ? (0.08838834764831845f * 1.4426950408889634f) : 1.0f;
    wbf[idx] = (__bf16)(src[e] * sc);
}

// ---------------------------------------------------------------------------
// Projection with fragment-swizzled output. grid 512, block 256 (4 waves).
// ---------------------------------------------------------------------------
#define TR_QK 132
#define TR_V  68

__global__ __launch_bounds__(256) void proj_kernel(
    const float* __restrict__ x, __bf16* __restrict__ ws)
{
    __shared__ __bf16 tr[128 * TR_V];

    const int lane = threadIdx.x & 63;
    const int wave = threadIdx.x >> 6;
    const int quad = lane >> 4;
    const int l16  = lane & 15;
    const int m0 = blockIdx.x * 64;
    const int b  = m0 / TT;
    const int t0 = m0 % TT;

    const __bf16* Wbf = ws + WBF_OFF;
    __bf16* Qs = ws;
    __bf16* Ks = ws + BTH;
    __bf16* Vs = ws + 2 * BTH;

    bf16x8 xf[4];
    #pragma unroll
    for (int ks = 0; ks < 4; ++ks)
        xf[ks] = load_cvt8(x + (size_t)(m0 + wave * 16 + l16) * CC + ks * 32 + quad * 8);

    #pragma unroll
    for (int which = 0; which < 2; ++which) {
        const __bf16* Wb = Wbf + (size_t)which * (128 * 128);
        __bf16* dst = which ? Ks : Qs;
        #pragma unroll
        for (int nt = 0; nt < 8; ++nt) {
            f32x4 acc = {0.f, 0.f, 0.f, 0.f};
            #pragma unroll
            for (int ks = 0; ks < 4; ++ks) {
                bf16x8 wf = *(const bf16x8*)(Wb + (size_t)(nt * 16 + l16) * CC + ks * 32 + quad * 8);
                acc = __builtin_amdgcn_mfma_f32_16x16x32_bf16(xf[ks], wf, acc, 0, 0, 0);
            }
            #pragma unroll
            for (int r = 0; r < 4; ++r)
                tr[(wave * 16 + quad * 4 + r) * TR_QK + nt * 16 + l16] = (__bf16)acc[r];
        }
        asm volatile("s_waitcnt lgkmcnt(0)" ::: "memory");
        #pragma unroll
        for (int ks = 0; ks < 4; ++ks) {
            const __bf16* p = &tr[(wave * 16 + l16) * TR_QK + ks * 32 + quad * 8];
            uint2 lo = *(const uint2*)p;
            uint2 hi = *(const uint2*)(p + 4);
            uint4 v; v.x = lo.x; v.y = lo.y; v.z = hi.x; v.w = hi.y;
            __bf16* o = dst + (((size_t)(b * 128 + t0 / 16 + wave) * 4 + ks) << 9) + lane * 8;
            *(uint4*)o = v;
        }
        asm volatile("s_waitcnt lgkmcnt(0)" ::: "memory");
    }

    __syncthreads();
    const __bf16* Wv = Wbf + 2 * (128 * 128);
    #pragma unroll
    for (int msub = 0; msub < 8; ++msub) {
        f32x4 acc = {0.f, 0.f, 0.f, 0.f};
        #pragma unroll
        for (int ks = 0; ks < 4; ++ks) {
            bf16x8 wf = *(const bf16x8*)(Wv + (size_t)(msub * 16 + l16) * CC + ks * 32 + quad * 8);
            acc = __builtin_amdgcn_mfma_f32_16x16x32_bf16(wf, xf[ks], acc, 0, 0, 0);
        }
        #pragma unroll
        for (int r = 0; r < 4; ++r)
            tr[(msub * 16 + quad * 4 + r) * TR_V + wave * 16 + l16] = (__bf16)acc[r];
    }
    __syncthreads();
    #pragma unroll
    for (int i = 0; i < 4; ++i) {
        int t32 = i >> 1;
        int h16 = wave * 2 + (i & 1);
        const __bf16* p = &tr[(h16 * 16 + l16) * TR_V + t32 * 32 + quad * 8];
        uint2 lo = *(const uint2*)p;
        uint2 hi = *(const uint2*)(p + 4);
        uint4 v; v.x = lo.x; v.y = lo.y; v.z = hi.x; v.w = hi.y;
        __bf16* o = Vs + (((size_t)(b * 64 + t0 / 32 + t32) * 8 + h16) << 9) + lane * 8;
        *(uint4*)o = v;
    }
}

// ---------------------------------------------------------------------------
// Split-K flash attention, double-buffered LDS staging, shuffle P-transpose.
// 128 q-rows/block, 32 q-rows/wave (2 subtiles). 1D grid (SPB*16),
// XCD-clustered batch decode. QK computed TRANSPOSED (A=K, B=Q) so the
// C->A-layout P conversion is an in-wave lane exchange (no LDS round-trip).
// Pipeline per iter: vmcnt(0) wait; barrier; issue stage(kt+1 -> other buf);
// compute(cur). Static-max softmax p = exp2(s - 16).
// ---------------------------------------------------------------------------
#define EXP_BIAS 16.0f

__global__ __launch_bounds__(256) void attn_kernel(
    const __bf16* __restrict__ ws, char* __restrict__ po,
    float* __restrict__ outp, int G, int SPB, int direct)
{
    __shared__ __bf16 ldsKV[2][16384];   // [buf][K 8192 | V 8192] = 2 x 32 KB

    const int lane = threadIdx.x & 63;
    const int wave = threadIdx.x >> 6;
    const int quad = lane >> 4;
    const int l16  = lane & 15;
    const int lane8 = lane * 8;

    const int lin = blockIdx.x;
    const int b  = (lin & 7) * 2 + ((lin >> 3) & 1);   // XCD-clustered batch
    const int s  = SPB - 1 - (lin >> 4);               // heavy slots first

    // slot -> (qt, seg)
    int acc = 0, qt = 0, seg = 0;
    for (int q = 0; q < NQT128; ++q) {
        int c = (2 * (q + 1) + G - 1) / G;
        if (s < acc + c) { qt = q; seg = s - acc; break; }
        acc += c;
    }
    const int kt0 = seg * G;
    int kt1 = 2 * (qt + 1);
    if (kt0 + G < kt1) kt1 = kt0 + G;
    const int segs_qt = (2 * (qt + 1) + G - 1) / G;
    const int dwrite = direct | (segs_qt == 1);        // single segment -> write out

    const int qw = qt * 128 + wave * 32;               // wave's first q row
    int kt1w = (qw + 32 + 63) >> 6;                    // wave causal clamp (excl)
    if (kt1w > kt1) kt1w = kt1;

    const __bf16* Qs = ws;
    const __bf16* Ks = ws + BTH;
    const __bf16* Vs = ws + 2 * BTH;

    bf16x8 qf[2][4];
    #pragma unroll
    for (int m = 0; m < 2; ++m)
        #pragma unroll
        for (int ks = 0; ks < 4; ++ks)
            qf[m][ks] = *(const bf16x8*)(Qs + (((size_t)(b * 128 + qt * 8 + wave * 2 + m) * 4 + ks) << 9) + lane8);

    float l_m[2] = {0.f, 0.f};
    f32x4 o[2][8];
    #pragma unroll
    for (int m = 0; m < 2; ++m)
        #pragma unroll
        for (int h8 = 0; h8 < 8; ++h8) o[m][h8] = (f32x4){0.f, 0.f, 0.f, 0.f};

    // ---- staging helper (8 chunks of 1 KB per wave; 32 per block) ---------
    #define STAGE(KT, BUF)                                                          \
        do {                                                                        \
            const char* kbase_ = (const char*)(Ks + (((size_t)(b * 128 + (KT) * 4) * 4) << 9)); \
            const char* vbase_ = (const char*)(Vs + (((size_t)(b * 64 + (KT) * 2) * 8) << 9));  \
            _Pragma("unroll")                                                       \
            for (int i_ = 0; i_ < 8; ++i_) {                                        \
                const int c_ = wave * 8 + i_;                                       \
                const char* g_ = (c_ < 16) ? (kbase_ + c_ * 1024)                   \
                                           : (vbase_ + (c_ - 16) * 1024);           \
                char* l_ = (char*)ldsKV[BUF] + c_ * 1024;                           \
                load_lds16(g_ + (size_t)lane * 16, l_);                             \
            }                                                                       \
        } while (0)

    STAGE(kt0, 0);
    int cur = 0;

    for (int kt = kt0; kt < kt1; ++kt) {
        asm volatile("s_waitcnt vmcnt(0)" ::: "memory");
        __syncthreads();
        if (kt + 1 < kt1) STAGE(kt + 1, cur ^ 1);

        if (kt < kt1w) {
            const int k0 = kt * 64;
            const char* ldsK = (const char*)ldsKV[cur];
            const char* ldsV = (const char*)ldsKV[cur] + 16384;

            // ---- S^T = K Q^T: C row(quad*4+r)=key, col(l16)=q -------------
            f32x4 s2[2][4];
            #pragma unroll
            for (int nsub = 0; nsub < 4; ++nsub) {
                bf16x8 kfr[4];
                #pragma unroll
                for (int ks = 0; ks < 4; ++ks)
                    kfr[ks] = *(const bf16x8*)(ldsK + ((nsub * 4 + ks) << 10) + lane * 16);
                #pragma unroll
                for (int m = 0; m < 2; ++m) {
                    f32x4 a2 = {0.f, 0.f, 0.f, 0.f};
                    #pragma unroll
                    for (int ks = 0; ks < 4; ++ks)
                        a2 = __builtin_amdgcn_mfma_f32_16x16x32_bf16(kfr[ks], qf[m][ks], a2, 0, 0, 0);
                    s2[m][nsub] = a2;
                }
            }

            // ---- mask + exp2 + per-lane l + shuffle-transpose to A-frags --
            #pragma unroll
            for (int m = 0; m < 2; ++m) {
                const int qrow = qw + m * 16 + l16;
                union PK { u64 u; __bf16 h[4]; } pk[4];
                #pragma unroll
                for (int nsub = 0; nsub < 4; ++nsub) {
                    #pragma unroll
                    for (int r = 0; r < 4; ++r) {
                        int key = k0 + nsub * 16 + quad * 4 + r;
                        float sv = (key > qrow) ? -3e38f : s2[m][nsub][r];
                        float p = __builtin_amdgcn_exp2f(sv - EXP_BIAS);
                        l_m[m] += p;
                        pk[nsub].h[r] = (__bf16)p;
                    }
                }

                const int srcA = (quad & 1) ? (l16 + 32) : l16;   // quad' = (quad&1)*2
                const int srcB = srcA + 16;
                const int hiSel = quad >> 1;
                bf16x8 pf[2];
                #pragma unroll
                for (int ks2 = 0; ks2 < 2; ++ks2) {
                    u64 a0 = __shfl(pk[2 * ks2].u, srcA, 64);
                    u64 a1 = __shfl(pk[2 * ks2 + 1].u, srcA, 64);
                    u64 b0 = __shfl(pk[2 * ks2].u, srcB, 64);
                    u64 b1 = __shfl(pk[2 * ks2 + 1].u, srcB, 64);
                    union { u64 v[2]; bf16x8 f; } uu;
                    uu.v[0] = hiSel ? a1 : a0;
                    uu.v[1] = hiSel ? b1 : b0;
                    pf[ks2] = uu.f;
                }

                // ---- O += P V (A=P, B=V^T frags from LDS) -----------------
                #pragma unroll
                for (int h8 = 0; h8 < 8; ++h8) {
                    bf16x8 v0 = *(const bf16x8*)(ldsV + ((0 * 8 + h8) << 10) + lane * 16);
                    bf16x8 v1 = *(const bf16x8*)(ldsV + ((1 * 8 + h8) << 10) + lane * 16);
                    o[m][h8] = __builtin_amdgcn_mfma_f32_16x16x32_bf16(pf[0], v0, o[m][h8], 0, 0, 0);
                    o[m][h8] = __builtin_amdgcn_mfma_f32_16x16x32_bf16(pf[1], v1, o[m][h8], 0, 0, 0);
                }
            }
        }
        cur ^= 1;
    }

    // ---- l: reduce across quads (per-lane q = l16-indexed) -----------------
    #pragma unroll
    for (int m = 0; m < 2; ++m) {
        l_m[m] += __shfl_xor(l_m[m], 16, 64);
        l_m[m] += __shfl_xor(l_m[m], 32, 64);
    }

    if (dwrite) {
        #pragma unroll
        for (int m = 0; m < 2; ++m) {
            float inv[4];
            #pragma unroll
            for (int r = 0; r < 4; ++r) {
                float lv = __shfl(l_m[m], (lane & 48) + quad * 4 + r, 64);
                inv[r] = 1.0f / lv;
            }
            #pragma unroll
            for (int h8 = 0; h8 < 8; ++h8)
                #pragma unroll
                for (int r = 0; r < 4; ++r)
                    outp[(size_t)(b * TT + qw + m * 16 + quad * 4 + r) * HH + h8 * 16 + l16] = o[m][h8][r] * inv[r];
        }
    } else {
        char* slot = po + (size_t)(b * SPB + s) * SLOT_BYTES;
        __bf16* slot_o = (__bf16*)slot;
        float*  slot_l = (float*)(slot + SLOT_L_OFF);
        #pragma unroll
        for (int m = 0; m < 2; ++m) {
            #pragma unroll
            for (int h8 = 0; h8 < 8; ++h8)
                #pragma unroll
                for (int r = 0; r < 4; ++r)
                    slot_o[(size_t)(wave * 32 + m * 16 + quad * 4 + r) * 128 + h8 * 16 + l16] = (__bf16)o[m][h8][r];
            if (quad == 0)
                slot_l[wave * 32 + m * 16 + l16] = l_m[m];
        }
    }
}

// ---------------------------------------------------------------------------
// Reduce: sum bf16 partial o + fp32 l over segments, normalize.
// grid (NQT128*4, 16), block 256. Block: 32 rows x 128 cols. Skips qtiles
// with a single segment (attn wrote them directly).
// ---------------------------------------------------------------------------
__global__ __launch_bounds__(256) void reduce_kernel(
    const char* __restrict__ po, float* __restrict__ outp, int G, int SPB)
{
    __shared__ float lsum[32];
    const int qt  = blockIdx.x >> 2;
    const int qtr = blockIdx.x & 3;
    const int b   = blockIdx.y;
    const int tid = threadIdx.x;

    const int segs = (2 * (qt + 1) + G - 1) / G;
    if (segs == 1) return;                       // attn wrote these directly

    int acc = 0;
    for (int qq = 0; qq < qt; ++qq) acc += (2 * (qq + 1) + G - 1) / G;
    const char* base = po + (size_t)(b * SPB + acc) * SLOT_BYTES;
    const int r0 = qtr * 32;

    if (tid < 32) {
        float v = 0.f;
        for (int sg = 0; sg < segs; ++sg)
            v += ((const float*)(base + (size_t)sg * SLOT_BYTES + SLOT_L_OFF))[r0 + tid];
        lsum[tid] = v;
    }
    __syncthreads();

    const int rsub = tid >> 4;                   // 0..15
    const int cg   = tid & 15;                   // cols cg*8 .. cg*8+7
    float a[2][8];
    #pragma unroll
    for (int p = 0; p < 2; ++p)
        #pragma unroll
        for (int j = 0; j < 8; ++j) a[p][j] = 0.f;

    for (int sg = 0; sg < segs; ++sg) {
        const char* sb = base + (size_t)sg * SLOT_BYTES;
        #pragma unroll
        for (int p = 0; p < 2; ++p) {
            int row = r0 + rsub + p * 16;
            union { uint4 u; __bf16 h[8]; } v;
            v.u = *(const uint4*)(sb + ((size_t)row * 128 + cg * 8) * 2);
            #pragma unroll
            for (int j = 0; j < 8; ++j) a[p][j] += (float)v.h[j];
        }
    }

    #pragma unroll
    for (int p = 0; p < 2; ++p) {
        int row = r0 + rsub + p * 16;
        float inv = 1.0f / lsum[rsub + p * 16];
        float* op = outp + (size_t)(b * TT + qt * 128 + row) * HH + cg * 8;
        float4 o0 = {a[p][0] * inv, a[p][1] * inv, a[p][2] * inv, a[p][3] * inv};
        float4 o1 = {a[p][4] * inv, a[p][5] * inv, a[p][6] * inv, a[p][7] * inv};
        *(float4*)op = o0;
        *(float4*)(op + 4) = o1;
    }
}

extern "C" void kernel_launch(void* const* d_in, const int* in_sizes, int n_in,
                              void* d_out, int out_size, void* d_ws, size_t ws_size,
                              hipStream_t stream)
{
    const float* x  = (const float*)d_in[0];
    const float* Wq = (const float*)d_in[1];
    const float* Wk = (const float*)d_in[2];
    const float* Wv = (const float*)d_in[3];
    __bf16* ws = (__bf16*)d_ws;
    float* out = (float*)d_out;
    char* po   = (char*)d_ws + PARTIAL_OFF_BYTES;

    int G = 0, SPB = 0, direct = 1;
    const int cand[3] = {6, 8, 16};
    for (int ci = 0; ci < 3; ++ci) {
        int g = cand[ci], spb = 0;
        for (int q = 0; q < NQT128; ++q) spb += (2 * (q + 1) + g - 1) / g;
        size_t need = PARTIAL_OFF_BYTES + (size_t)spb * BB * SLOT_BYTES;
        if (need <= ws_size) { G = g; SPB = spb; direct = 0; break; }
    }
    if (direct) { G = 2 * NQT128; SPB = NQT128; }   // one segment per qtile

    wcvt_kernel<<<192, 256, 0, stream>>>(Wq, Wk, Wv, ws + WBF_OFF);
    proj_kernel<<<512, 256, 0, stream>>>(x, ws);
    attn_kernel<<<SPB * 16, 256, 0, stream>>>(ws, po, out, G, SPB, direct);
    if (!direct) {
        dim3 rgrid(NQT128 * 4, BB);
        reduce_kernel<<<rgrid, 256, 0, stream>>>(po, out, G, SPB);
    }
}

// Round 9
// 143.376 us; speedup vs baseline: 1.0612x; 1.0612x over previous
//
#include <hip/hip_runtime.h>
#include <hip/hip_bf16.h>

// Problem constants
#define BB 16
#define TT 2048
#define CC 128
#define HH 128
#define NQT128 16          // q tiles of 128 rows

typedef __bf16 bf16x8 __attribute__((ext_vector_type(8)));
typedef float  f32x4  __attribute__((ext_vector_type(4)));

// ws layout (bf16 elems unless noted):
//   Qs  [b][tt16 128][ks 4][lane 64][j 8]   (exp2-domain scale folded)
//   Ks  [b][tt16 128][ks 4][lane 64][j 8]   (one 64-key tile = 16 KB contig)
//   Vs  [b][t32 64][h16 8][lane 64][j 8]    (one 64-key tile = 16 KB contig)
//   Wbf 3*128*128 FRAGMENT-SWIZZLED: [which][blk16 8][ks 4][lane 64][j 8]
//   partial slots: bf16 o[128*128] (32768 B) + float l[128] (512 B)
#define BTH       ((size_t)BB * TT * HH)
#define WBF_OFF   (3 * BTH)
#define PARTIAL_OFF_BYTES (3 * BTH * 2 + 3 * 128 * 128 * 2)
#define SLOT_BYTES 33280
#define SLOT_L_OFF 32768

static __device__ __forceinline__ bf16x8 load_cvt8(const float* p) {
    float4 a = *(const float4*)p;
    float4 b = *(const float4*)(p + 4);
    bf16x8 r;
    r[0] = (__bf16)a.x; r[1] = (__bf16)a.y; r[2] = (__bf16)a.z; r[3] = (__bf16)a.w;
    r[4] = (__bf16)b.x; r[5] = (__bf16)b.y; r[6] = (__bf16)b.z; r[7] = (__bf16)b.w;
    return r;
}

// async global->LDS, 16 B/lane: data lands at lds_base + lane*16
static __device__ __forceinline__ void load_lds16(const void* g, void* l) {
    __builtin_amdgcn_global_load_lds(
        (const __attribute__((address_space(1))) unsigned int*)g,
        (__attribute__((address_space(3))) unsigned int*)l, 16, 0, 0);
}

// light barriers: do NOT drain vmcnt (keeps prefetch DMA in flight)
#define BAR_VM()   asm volatile("s_waitcnt vmcnt(0)\n\ts_barrier" ::: "memory")
#define BAR_LGKM() asm volatile("s_waitcnt lgkmcnt(0)\n\ts_barrier" ::: "memory")

// ---------------------------------------------------------------------------
// W pre-convert + FRAGMENT SWIZZLE: fp32 -> bf16 in MFMA fragment order so
// proj's W loads are wave-uniform base + lane*16B. Wq scaled by C^-0.5*log2e.
// 6144 threads, each writes one 8-elem fragment slice.
// ---------------------------------------------------------------------------
__global__ __launch_bounds__(256) void wcvt_kernel(
    const float* __restrict__ Wq, const float* __restrict__ Wk,
    const float* __restrict__ Wv, __bf16* __restrict__ wbf)
{
    int idx = blockIdx.x * 256 + threadIdx.x;          // < 6144
    int which = idx >> 11;
    int rem = idx & 2047;
    int blk = rem >> 8;            // 0..7 (16-row block)
    int r2  = rem & 255;
    int ks   = r2 >> 6;
    int lane = r2 & 63;
    int quad = lane >> 4, l16 = lane & 15;
    const float* src = (which == 0) ? Wq : (which == 1) ? Wk : Wv;
    float sc = (which == 0) ? (0.08838834764831845f * 1.4426950408889634f) : 1.0f;
    const float* p = src + (size_t)(blk * 16 + l16) * CC + ks * 32 + quad * 8;
    bf16x8 v;
    #pragma unroll
    for (int j = 0; j < 8; ++j) v[j] = (__bf16)(p[j] * sc);
    *(bf16x8*)(wbf + (size_t)which * 16384 + (((size_t)(blk * 4 + ks)) << 9) + lane * 8) = v;
}

// ---------------------------------------------------------------------------
// Projection, fully coalesced: x staged into padded LDS (132-float rows ->
// 2-way banks, free), W read from fragment-swizzled Wbf. grid 512, block 256.
// ---------------------------------------------------------------------------
#define TR_QK 132
#define TR_V  68

__global__ __launch_bounds__(256) void proj_kernel(
    const float* __restrict__ x, __bf16* __restrict__ ws)
{
    __shared__ float  xs[64 * 132];       // 33792 B
    __shared__ __bf16 tr[128 * TR_V];     // 17408 B

    const int lane = threadIdx.x & 63;
    const int wave = threadIdx.x >> 6;
    const int quad = lane >> 4;
    const int l16  = lane & 15;
    const int tid  = threadIdx.x;
    const int m0 = blockIdx.x * 64;
    const int b  = m0 / TT;
    const int t0 = m0 % TT;

    const __bf16* Wbf = ws + WBF_OFF;
    __bf16* Qs = ws;
    __bf16* Ks = ws + BTH;
    __bf16* Vs = ws + 2 * BTH;

    // ---- stage x tile (64 x 128 fp32) coalesced -> padded LDS --------------
    const float* xg = x + (size_t)m0 * CC;
    #pragma unroll
    for (int t = 0; t < 8; ++t) {
        int f = t * 256 + tid;            // float4 id
        int row = f >> 5, c4 = f & 31;
        float4 v = *(const float4*)(xg + (size_t)f * 4);
        *(float4*)(&xs[row * 132 + c4 * 4]) = v;
    }
    __syncthreads();

    bf16x8 xf[4];
    #pragma unroll
    for (int ks = 0; ks < 4; ++ks)
        xf[ks] = load_cvt8(&xs[(wave * 16 + l16) * 132 + ks * 32 + quad * 8]);

    #pragma unroll
    for (int which = 0; which < 2; ++which) {
        const __bf16* Wb = Wbf + (size_t)which * 16384;
        __bf16* dst = which ? Ks : Qs;
        #pragma unroll
        for (int nt = 0; nt < 8; ++nt) {
            f32x4 acc = {0.f, 0.f, 0.f, 0.f};
            #pragma unroll
            for (int ks = 0; ks < 4; ++ks) {
                bf16x8 wf = *(const bf16x8*)(Wb + (((size_t)(nt * 4 + ks)) << 9) + lane * 8);
                acc = __builtin_amdgcn_mfma_f32_16x16x32_bf16(xf[ks], wf, acc, 0, 0, 0);
            }
            #pragma unroll
            for (int r = 0; r < 4; ++r)
                tr[(wave * 16 + quad * 4 + r) * TR_QK + nt * 16 + l16] = (__bf16)acc[r];
        }
        asm volatile("s_waitcnt lgkmcnt(0)" ::: "memory");
        #pragma unroll
        for (int ks = 0; ks < 4; ++ks) {
            const __bf16* p = &tr[(wave * 16 + l16) * TR_QK + ks * 32 + quad * 8];
            uint2 lo = *(const uint2*)p;
            uint2 hi = *(const uint2*)(p + 4);
            uint4 v; v.x = lo.x; v.y = lo.y; v.z = hi.x; v.w = hi.y;
            __bf16* o = dst + (((size_t)(b * 128 + t0 / 16 + wave) * 4 + ks) << 9) + lane * 8;
            *(uint4*)o = v;
        }
        asm volatile("s_waitcnt lgkmcnt(0)" ::: "memory");
    }

    __syncthreads();
    const __bf16* Wv = Wbf + 2 * 16384;
    #pragma unroll
    for (int msub = 0; msub < 8; ++msub) {
        f32x4 acc = {0.f, 0.f, 0.f, 0.f};
        #pragma unroll
        for (int ks = 0; ks < 4; ++ks) {
            bf16x8 wf = *(const bf16x8*)(Wv + (((size_t)(msub * 4 + ks)) << 9) + lane * 8);
            acc = __builtin_amdgcn_mfma_f32_16x16x32_bf16(wf, xf[ks], acc, 0, 0, 0);
        }
        #pragma unroll
        for (int r = 0; r < 4; ++r)
            tr[(msub * 16 + quad * 4 + r) * TR_V + wave * 16 + l16] = (__bf16)acc[r];
    }
    __syncthreads();
    #pragma unroll
    for (int i = 0; i < 4; ++i) {
        int t32 = i >> 1;
        int h16 = wave * 2 + (i & 1);
        const __bf16* p = &tr[(h16 * 16 + l16) * TR_V + t32 * 32 + quad * 8];
        uint2 lo = *(const uint2*)p;
        uint2 hi = *(const uint2*)(p + 4);
        uint4 v; v.x = lo.x; v.y = lo.y; v.z = hi.x; v.w = hi.y;
        __bf16* o = Vs + (((size_t)(b * 64 + t0 / 32 + t32) * 8 + h16) << 9) + lane * 8;
        *(uint4*)o = v;
    }
}

// ---------------------------------------------------------------------------
// Split-K flash attention. 128 q-rows/block, 32/wave. Single K + single V
// LDS buffer (3 blocks/CU) with 3 LIGHT barriers per iter (raw s_barrier,
// no vmcnt drain): K(kt+1) DMA overlaps softmax+P+PV of tile kt.
// P transpose via wave-private LDS (S_LDS=76: 0 conflicts measured).
// Static-max softmax p = exp2(s - 16); bf16 partials; single-seg direct write.
// ---------------------------------------------------------------------------
#define S_LDS 76
#define EXP_BIAS 16.0f

__global__ __launch_bounds__(256) void attn_kernel(
    const __bf16* __restrict__ ws, char* __restrict__ po,
    float* __restrict__ outp, int G, int SPB, int direct)
{
    __shared__ __bf16 ldsK[8192];               // 16 KB
    __shared__ __bf16 ldsV[8192];               // 16 KB
    __shared__ __bf16 lds_p[4 * 32 * S_LDS];    // 19456 B -> total 52224

    const int lane = threadIdx.x & 63;
    const int wave = threadIdx.x >> 6;
    const int quad = lane >> 4;
    const int l16  = lane & 15;
    const int lane8 = lane * 8;

    const int lin = blockIdx.x;
    const int b  = (lin & 7) * 2 + ((lin >> 3) & 1);   // XCD-clustered batch
    const int s  = SPB - 1 - (lin >> 4);               // heavy slots first

    // slot -> (qt, seg)
    int acc = 0, qt = 0, seg = 0;
    for (int q = 0; q < NQT128; ++q) {
        int c = (2 * (q + 1) + G - 1) / G;
        if (s < acc + c) { qt = q; seg = s - acc; break; }
        acc += c;
    }
    const int kt0 = seg * G;
    int kt1 = 2 * (qt + 1);
    if (kt0 + G < kt1) kt1 = kt0 + G;
    const int segs_qt = (2 * (qt + 1) + G - 1) / G;
    const int dwrite = direct | (segs_qt == 1);

    const int qw = qt * 128 + wave * 32;               // wave's first q row
    int kt1w = (qw + 32 + 63) >> 6;                    // wave causal clamp
    if (kt1w > kt1) kt1w = kt1;

    const __bf16* Qs = ws;
    const __bf16* Ks = ws + BTH;
    const __bf16* Vs = ws + 2 * BTH;

    bf16x8 qf[2][4];
    #pragma unroll
    for (int m = 0; m < 2; ++m)
        #pragma unroll
        for (int ks = 0; ks < 4; ++ks)
            qf[m][ks] = *(const bf16x8*)(Qs + (((size_t)(b * 128 + qt * 8 + wave * 2 + m) * 4 + ks) << 9) + lane8);

    float l_r[2][4];
    f32x4 o[2][8];
    #pragma unroll
    for (int m = 0; m < 2; ++m) {
        #pragma unroll
        for (int r = 0; r < 4; ++r) l_r[m][r] = 0.f;
        #pragma unroll
        for (int h8 = 0; h8 < 8; ++h8) o[m][h8] = (f32x4){0.f, 0.f, 0.f, 0.f};
    }

    __bf16* myP = lds_p + wave * 32 * S_LDS;

    // staging: 16 chunks of 1 KB each for K and V (4 per wave)
    #define STAGE_K(KT)                                                             \
        do {                                                                        \
            const char* kb_ = (const char*)(Ks + (((size_t)(b * 128 + (KT) * 4) * 4) << 9)); \
            _Pragma("unroll")                                                       \
            for (int i_ = 0; i_ < 4; ++i_) {                                        \
                int c_ = wave * 4 + i_;                                             \
                load_lds16(kb_ + c_ * 1024 + (size_t)lane * 16, (char*)ldsK + c_ * 1024); \
            }                                                                       \
        } while (0)
    #define STAGE_V(KT)                                                             \
        do {                                                                        \
            const char* vb_ = (const char*)(Vs + (((size_t)(b * 64 + (KT) * 2) * 8) << 9)); \
            _Pragma("unroll")                                                       \
            for (int i_ = 0; i_ < 4; ++i_) {                                        \
                int c_ = wave * 4 + i_;                                             \
                load_lds16(vb_ + c_ * 1024 + (size_t)lane * 16, (char*)ldsV + c_ * 1024); \
            }                                                                       \
        } while (0)

    STAGE_K(kt0);
    STAGE_V(kt0);

    for (int kt = kt0; kt < kt1; ++kt) {
        BAR_VM();                                  // tile kt fully in LDS

        f32x4 s2[2][4];
        if (kt < kt1w) {
            // ---- S = Q K^T (K frags from LDS) -----------------------------
            #pragma unroll
            for (int nsub = 0; nsub < 4; ++nsub) {
                bf16x8 kfr[4];
                #pragma unroll
                for (int ks = 0; ks < 4; ++ks)
                    kfr[ks] = *(const bf16x8*)((const char*)ldsK + ((nsub * 4 + ks) << 10) + lane * 16);
                #pragma unroll
                for (int m = 0; m < 2; ++m) {
                    f32x4 a2 = {0.f, 0.f, 0.f, 0.f};
                    #pragma unroll
                    for (int ks = 0; ks < 4; ++ks)
                        a2 = __builtin_amdgcn_mfma_f32_16x16x32_bf16(qf[m][ks], kfr[ks], a2, 0, 0, 0);
                    s2[m][nsub] = a2;
                }
            }
        }
        BAR_LGKM();                                // all waves done with ldsK
        if (kt + 1 < kt1) STAGE_K(kt + 1);         // K DMA flies under phase 2

        if (kt < kt1w) {
            const int k0 = kt * 64;
            // ---- mask + exp2 + lane-local l + P write ---------------------
            #pragma unroll
            for (int m = 0; m < 2; ++m) {
                const int qr0m = qw + m * 16;
                if (k0 + 63 > qr0m) {
                    #pragma unroll
                    for (int nsub = 0; nsub < 4; ++nsub) {
                        int key = k0 + nsub * 16 + l16;
                        #pragma unroll
                        for (int r = 0; r < 4; ++r) {
                            int rowq = qr0m + quad * 4 + r;
                            if (key > rowq) s2[m][nsub][r] = -3e38f;
                        }
                    }
                }
                #pragma unroll
                for (int nsub = 0; nsub < 4; ++nsub) {
                    #pragma unroll
                    for (int r = 0; r < 4; ++r) {
                        float p = __builtin_amdgcn_exp2f(s2[m][nsub][r] - EXP_BIAS);
                        l_r[m][r] += p;
                        myP[(m * 16 + quad * 4 + r) * S_LDS + nsub * 16 + l16] = (__bf16)p;
                    }
                }
            }
            asm volatile("s_waitcnt lgkmcnt(0)" ::: "memory");

            // ---- P: C-layout -> A-layout ----------------------------------
            bf16x8 pf[2][2];
            #pragma unroll
            for (int m = 0; m < 2; ++m)
                #pragma unroll
                for (int ks2 = 0; ks2 < 2; ++ks2) {
                    union { bf16x8 v; uint2 h[2]; } u;
                    const char* base = (const char*)myP + (size_t)(m * 16 + l16) * (S_LDS * 2) + ks2 * 64 + quad * 16;
                    u.h[0] = *(const uint2*)base;
                    u.h[1] = *(const uint2*)(base + 8);
                    pf[m][ks2] = u.v;
                }

            // ---- O += P V (V frags from LDS) ------------------------------
            #pragma unroll
            for (int h8 = 0; h8 < 8; ++h8) {
                bf16x8 v0 = *(const bf16x8*)((const char*)ldsV + ((0 * 8 + h8) << 10) + lane * 16);
                bf16x8 v1 = *(const bf16x8*)((const char*)ldsV + ((1 * 8 + h8) << 10) + lane * 16);
                #pragma unroll
                for (int m = 0; m < 2; ++m) {
                    o[m][h8] = __builtin_amdgcn_mfma_f32_16x16x32_bf16(pf[m][0], v0, o[m][h8], 0, 0, 0);
                    o[m][h8] = __builtin_amdgcn_mfma_f32_16x16x32_bf16(pf[m][1], v1, o[m][h8], 0, 0, 0);
                }
            }
        }
        BAR_LGKM();                                // all waves done with ldsV
        if (kt + 1 < kt1) STAGE_V(kt + 1);         // V DMA over loop backedge
    }

    // l reduction across the 16-lane row group
    #pragma unroll
    for (int m = 0; m < 2; ++m)
        #pragma unroll
        for (int r = 0; r < 4; ++r)
            #pragma unroll
            for (int j = 1; j <= 8; j <<= 1)
                l_r[m][r] += __shfl_xor(l_r[m][r], j, 64);

    if (dwrite) {
        #pragma unroll
        for (int m = 0; m < 2; ++m) {
            float inv[4];
            #pragma unroll
            for (int r = 0; r < 4; ++r) inv[r] = 1.0f / l_r[m][r];
            #pragma unroll
            for (int h8 = 0; h8 < 8; ++h8)
                #pragma unroll
                for (int r = 0; r < 4; ++r)
                    outp[(size_t)(b * TT + qw + m * 16 + quad * 4 + r) * HH + h8 * 16 + l16] = o[m][h8][r] * inv[r];
        }
    } else {
        char* slot = po + (size_t)(b * SPB + s) * SLOT_BYTES;
        __bf16* slot_o = (__bf16*)slot;
        float*  slot_l = (float*)(slot + SLOT_L_OFF);
        #pragma unroll
        for (int m = 0; m < 2; ++m) {
            #pragma unroll
            for (int h8 = 0; h8 < 8; ++h8)
                #pragma unroll
                for (int r = 0; r < 4; ++r)
                    slot_o[(size_t)(wave * 32 + m * 16 + quad * 4 + r) * 128 + h8 * 16 + l16] = (__bf16)o[m][h8][r];
            if (l16 == 0) {
                #pragma unroll
                for (int r = 0; r < 4; ++r)
                    slot_l[wave * 32 + m * 16 + quad * 4 + r] = l_r[m][r];
            }
        }
    }
}

// ---------------------------------------------------------------------------
// Reduce: sum bf16 partial o + fp32 l over segments, normalize.
// grid (NQT128*4, 16), block 256. Skips single-segment qtiles.
// ---------------------------------------------------------------------------
__global__ __launch_bounds__(256) void reduce_kernel(
    const char* __restrict__ po, float* __restrict__ outp, int G, int SPB)
{
    __shared__ float lsum[32];
    const int qt  = blockIdx.x >> 2;
    const int qtr = blockIdx.x & 3;
    const int b   = blockIdx.y;
    const int tid = threadIdx.x;

    const int segs = (2 * (qt + 1) + G - 1) / G;
    if (segs == 1) return;

    int acc = 0;
    for (int qq = 0; qq < qt; ++qq) acc += (2 * (qq + 1) + G - 1) / G;
    const char* base = po + (size_t)(b * SPB + acc) * SLOT_BYTES;
    const int r0 = qtr * 32;

    if (tid < 32) {
        float v = 0.f;
        for (int sg = 0; sg < segs; ++sg)
            v += ((const float*)(base + (size_t)sg * SLOT_BYTES + SLOT_L_OFF))[r0 + tid];
        lsum[tid] = v;
    }
    __syncthreads();

    const int rsub = tid >> 4;
    const int cg   = tid & 15;
    float a[2][8];
    #pragma unroll
    for (int p = 0; p < 2; ++p)
        #pragma unroll
        for (int j = 0; j < 8; ++j) a[p][j] = 0.f;

    for (int sg = 0; sg < segs; ++sg) {
        const char* sb = base + (size_t)sg * SLOT_BYTES;
        #pragma unroll
        for (int p = 0; p < 2; ++p) {
            int row = r0 + rsub + p * 16;
            union { uint4 u; __bf16 h[8]; } v;
            v.u = *(const uint4*)(sb + ((size_t)row * 128 + cg * 8) * 2);
            #pragma unroll
            for (int j = 0; j < 8; ++j) a[p][j] += (float)v.h[j];
        }
    }

    #pragma unroll
    for (int p = 0; p < 2; ++p) {
        int row = r0 + rsub + p * 16;
        float inv = 1.0f / lsum[rsub + p * 16];
        float* op = outp + (size_t)(b * TT + qt * 128 + row) * HH + cg * 8;
        float4 o0 = {a[p][0] * inv, a[p][1] * inv, a[p][2] * inv, a[p][3] * inv};
        float4 o1 = {a[p][4] * inv, a[p][5] * inv, a[p][6] * inv, a[p][7] * inv};
        *(float4*)op = o0;
        *(float4*)(op + 4) = o1;
    }
}

extern "C" void kernel_launch(void* const* d_in, const int* in_sizes, int n_in,
                              void* d_out, int out_size, void* d_ws, size_t ws_size,
                              hipStream_t stream)
{
    const float* x  = (const float*)d_in[0];
    const float* Wq = (const float*)d_in[1];
    const float* Wk = (const float*)d_in[2];
    const float* Wv = (const float*)d_in[3];
    __bf16* ws = (__bf16*)d_ws;
    float* out = (float*)d_out;
    char* po   = (char*)d_ws + PARTIAL_OFF_BYTES;

    int G = 0, SPB = 0, direct = 1;
    const int cand[3] = {6, 8, 16};
    for (int ci = 0; ci < 3; ++ci) {
        int g = cand[ci], spb = 0;
        for (int q = 0; q < NQT128; ++q) spb += (2 * (q + 1) + g - 1) / g;
        size_t need = PARTIAL_OFF_BYTES + (size_t)spb * BB * SLOT_BYTES;
        if (need <= ws_size) { G = g; SPB = spb; direct = 0; break; }
    }
    if (direct) { G = 2 * NQT128; SPB = NQT128; }

    wcvt_kernel<<<24, 256, 0, stream>>>(Wq, Wk, Wv, ws + WBF_OFF);
    proj_kernel<<<512, 256, 0, stream>>>(x, ws);
    attn_kernel<<<SPB * 16, 256, 0, stream>>>(ws, po, out, G, SPB, direct);
    if (!direct) {
        dim3 rgrid(NQT128 * 4, BB);
        reduce_kernel<<<rgrid, 256, 0, stream>>>(po, out, G, SPB);
    }
}

// Round 10
// 135.450 us; speedup vs baseline: 1.1233x; 1.0585x over previous
//
#include <hip/hip_runtime.h>
#include <hip/hip_bf16.h>

// Problem constants
#define BB 16
#define TT 2048
#define CC 128
#define HH 128
#define NQT128 16          // q tiles of 128 rows

typedef __bf16 bf16x8 __attribute__((ext_vector_type(8)));
typedef float  f32x4  __attribute__((ext_vector_type(4)));

// ws layout (bf16 elems unless noted):
//   Qs  [b][tt16 128][ks 4][lane 64][j 8]   (exp2-domain scale folded)
//   Ks  [b][tt16 128][ks 4][lane 64][j 8]   (32-key tile = 8 KB contig)
//   Vs  [b][t32 64][h16 8][lane 64][j 8]    (32-key tile = 8 KB contig)
//   Wbf 3*128*128 FRAGMENT-SWIZZLED: [which][blk16 8][ks 4][lane 64][j 8]
//   partial slots: bf16 o[128*128] (32768 B) + float l[128] (512 B)
#define BTH       ((size_t)BB * TT * HH)
#define WBF_OFF   (3 * BTH)
#define PARTIAL_OFF_BYTES (3 * BTH * 2 + 3 * 128 * 128 * 2)
#define SLOT_BYTES 33280
#define SLOT_L_OFF 32768

static __device__ __forceinline__ bf16x8 load_cvt8(const float* p) {
    float4 a = *(const float4*)p;
    float4 b = *(const float4*)(p + 4);
    bf16x8 r;
    r[0] = (__bf16)a.x; r[1] = (__bf16)a.y; r[2] = (__bf16)a.z; r[3] = (__bf16)a.w;
    r[4] = (__bf16)b.x; r[5] = (__bf16)b.y; r[6] = (__bf16)b.z; r[7] = (__bf16)b.w;
    return r;
}

// async global->LDS, 16 B/lane: data lands at lds_base + lane*16
static __device__ __forceinline__ void load_lds16(const void* g, void* l) {
    __builtin_amdgcn_global_load_lds(
        (const __attribute__((address_space(1))) unsigned int*)g,
        (__attribute__((address_space(3))) unsigned int*)l, 16, 0, 0);
}

// barriers with targeted waitcnts (never drain the other counter)
#define BAR_VM()   asm volatile("s_waitcnt vmcnt(0)\n\ts_barrier" ::: "memory")
#define BAR_LGKM() asm volatile("s_waitcnt lgkmcnt(0)\n\ts_barrier" ::: "memory")

// ---------------------------------------------------------------------------
// W pre-convert + FRAGMENT SWIZZLE (proj W loads become lane*16B coalesced).
// ---------------------------------------------------------------------------
__global__ __launch_bounds__(256) void wcvt_kernel(
    const float* __restrict__ Wq, const float* __restrict__ Wk,
    const float* __restrict__ Wv, __bf16* __restrict__ wbf)
{
    int idx = blockIdx.x * 256 + threadIdx.x;          // < 6144
    int which = idx >> 11;
    int rem = idx & 2047;
    int blk = rem >> 8;
    int r2  = rem & 255;
    int ks   = r2 >> 6;
    int lane = r2 & 63;
    int quad = lane >> 4, l16 = lane & 15;
    const float* src = (which == 0) ? Wq : (which == 1) ? Wk : Wv;
    float sc = (which == 0) ? (0.08838834764831845f * 1.4426950408889634f) : 1.0f;
    const float* p = src + (size_t)(blk * 16 + l16) * CC + ks * 32 + quad * 8;
    bf16x8 v;
    #pragma unroll
    for (int j = 0; j < 8; ++j) v[j] = (__bf16)(p[j] * sc);
    *(bf16x8*)(wbf + (size_t)which * 16384 + (((size_t)(blk * 4 + ks)) << 9) + lane * 8) = v;
}

// ---------------------------------------------------------------------------
// Projection, fully coalesced (x via padded LDS, W fragment-swizzled).
// ---------------------------------------------------------------------------
#define TR_QK 132
#define TR_V  68

__global__ __launch_bounds__(256) void proj_kernel(
    const float* __restrict__ x, __bf16* __restrict__ ws)
{
    __shared__ float  xs[64 * 132];
    __shared__ __bf16 tr[128 * TR_V];

    const int lane = threadIdx.x & 63;
    const int wave = threadIdx.x >> 6;
    const int quad = lane >> 4;
    const int l16  = lane & 15;
    const int tid  = threadIdx.x;
    const int m0 = blockIdx.x * 64;
    const int b  = m0 / TT;
    const int t0 = m0 % TT;

    const __bf16* Wbf = ws + WBF_OFF;
    __bf16* Qs = ws;
    __bf16* Ks = ws + BTH;
    __bf16* Vs = ws + 2 * BTH;

    const float* xg = x + (size_t)m0 * CC;
    #pragma unroll
    for (int t = 0; t < 8; ++t) {
        int f = t * 256 + tid;
        int row = f >> 5, c4 = f & 31;
        float4 v = *(const float4*)(xg + (size_t)f * 4);
        *(float4*)(&xs[row * 132 + c4 * 4]) = v;
    }
    __syncthreads();

    bf16x8 xf[4];
    #pragma unroll
    for (int ks = 0; ks < 4; ++ks)
        xf[ks] = load_cvt8(&xs[(wave * 16 + l16) * 132 + ks * 32 + quad * 8]);

    #pragma unroll
    for (int which = 0; which < 2; ++which) {
        const __bf16* Wb = Wbf + (size_t)which * 16384;
        __bf16* dst = which ? Ks : Qs;
        #pragma unroll
        for (int nt = 0; nt < 8; ++nt) {
            f32x4 acc = {0.f, 0.f, 0.f, 0.f};
            #pragma unroll
            for (int ks = 0; ks < 4; ++ks) {
                bf16x8 wf = *(const bf16x8*)(Wb + (((size_t)(nt * 4 + ks)) << 9) + lane * 8);
                acc = __builtin_amdgcn_mfma_f32_16x16x32_bf16(xf[ks], wf, acc, 0, 0, 0);
            }
            #pragma unroll
            for (int r = 0; r < 4; ++r)
                tr[(wave * 16 + quad * 4 + r) * TR_QK + nt * 16 + l16] = (__bf16)acc[r];
        }
        asm volatile("s_waitcnt lgkmcnt(0)" ::: "memory");
        #pragma unroll
        for (int ks = 0; ks < 4; ++ks) {
            const __bf16* p = &tr[(wave * 16 + l16) * TR_QK + ks * 32 + quad * 8];
            uint2 lo = *(const uint2*)p;
            uint2 hi = *(const uint2*)(p + 4);
            uint4 v; v.x = lo.x; v.y = lo.y; v.z = hi.x; v.w = hi.y;
            __bf16* o = dst + (((size_t)(b * 128 + t0 / 16 + wave) * 4 + ks) << 9) + lane * 8;
            *(uint4*)o = v;
        }
        asm volatile("s_waitcnt lgkmcnt(0)" ::: "memory");
    }

    __syncthreads();
    const __bf16* Wv = Wbf + 2 * 16384;
    #pragma unroll
    for (int msub = 0; msub < 8; ++msub) {
        f32x4 acc = {0.f, 0.f, 0.f, 0.f};
        #pragma unroll
        for (int ks = 0; ks < 4; ++ks) {
            bf16x8 wf = *(const bf16x8*)(Wv + (((size_t)(msub * 4 + ks)) << 9) + lane * 8);
            acc = __builtin_amdgcn_mfma_f32_16x16x32_bf16(wf, xf[ks], acc, 0, 0, 0);
        }
        #pragma unroll
        for (int r = 0; r < 4; ++r)
            tr[(msub * 16 + quad * 4 + r) * TR_V + wave * 16 + l16] = (__bf16)acc[r];
    }
    __syncthreads();
    #pragma unroll
    for (int i = 0; i < 4; ++i) {
        int t32 = i >> 1;
        int h16 = wave * 2 + (i & 1);
        const __bf16* p = &tr[(h16 * 16 + l16) * TR_V + t32 * 32 + quad * 8];
        uint2 lo = *(const uint2*)p;
        uint2 hi = *(const uint2*)(p + 4);
        uint4 v; v.x = lo.x; v.y = lo.y; v.z = hi.x; v.w = hi.y;
        __bf16* o = Vs + (((size_t)(b * 64 + t0 / 32 + t32) * 8 + h16) << 9) + lane * 8;
        *(uint4*)o = v;
    }
}

// ---------------------------------------------------------------------------
// Split-K flash attention, 32-key tiles, TRUE double-buffered LDS staging.
// Per iter: [vmcnt(0)+bar] issue STAGE(tt+1 -> other buf); compute(tt);
// [lgkmcnt(0)+bar]. Buffer tt's slot is rewritten only at tt+2 (two barriers
// later) -> race-free. 43 KB LDS -> 3 blocks/CU keeps inter-block overlap.
// ---------------------------------------------------------------------------
#define S32 40
#define EXP_BIAS 16.0f

__global__ __launch_bounds__(256) void attn_kernel(
    const __bf16* __restrict__ ws, char* __restrict__ po,
    float* __restrict__ outp, int G, int SPB, int direct)
{
    __shared__ __bf16 ldsK[2][4096];            // 2 x 8 KB
    __shared__ __bf16 ldsV[2][4096];            // 2 x 8 KB
    __shared__ __bf16 lds_p[4 * 32 * S32];      // 10240 B  -> total 43008

    const int lane = threadIdx.x & 63;
    const int wave = threadIdx.x >> 6;
    const int quad = lane >> 4;
    const int l16  = lane & 15;
    const int lane8 = lane * 8;

    const int lin = blockIdx.x;
    const int b  = (lin & 7) * 2 + ((lin >> 3) & 1);   // XCD-clustered batch
    const int s  = SPB - 1 - (lin >> 4);               // heavy slots first

    // slot -> (qt, seg) in 64-key units, then convert to 32-key tiles
    int acc = 0, qt = 0, seg = 0;
    for (int q = 0; q < NQT128; ++q) {
        int c = (2 * (q + 1) + G - 1) / G;
        if (s < acc + c) { qt = q; seg = s - acc; break; }
        acc += c;
    }
    const int kt0 = seg * G;
    int kt1 = 2 * (qt + 1);
    if (kt0 + G < kt1) kt1 = kt0 + G;
    const int segs_qt = (2 * (qt + 1) + G - 1) / G;
    const int dwrite = direct | (segs_qt == 1);

    const int tt0 = kt0 * 2, tt1 = kt1 * 2;            // 32-key tiles
    const int qw = qt * 128 + wave * 32;               // wave's first q row
    int ttw = (qw + 63) >> 5;                          // wave causal clamp
    if (ttw > tt1) ttw = tt1;

    const __bf16* Qs = ws;
    const __bf16* Ks = ws + BTH;
    const __bf16* Vs = ws + 2 * BTH;

    bf16x8 qf[2][4];
    #pragma unroll
    for (int m = 0; m < 2; ++m)
        #pragma unroll
        for (int ks = 0; ks < 4; ++ks)
            qf[m][ks] = *(const bf16x8*)(Qs + (((size_t)(b * 128 + qt * 8 + wave * 2 + m) * 4 + ks) << 9) + lane8);

    float l_r[2][4];
    f32x4 o[2][8];
    #pragma unroll
    for (int m = 0; m < 2; ++m) {
        #pragma unroll
        for (int r = 0; r < 4; ++r) l_r[m][r] = 0.f;
        #pragma unroll
        for (int h8 = 0; h8 < 8; ++h8) o[m][h8] = (f32x4){0.f, 0.f, 0.f, 0.f};
    }

    __bf16* myP = lds_p + wave * 32 * S32;

    // stage one 32-key tile (K 8KB + V 8KB; 2 chunks of each per wave)
    #define STAGE32(TTv, BUF)                                                       \
        do {                                                                        \
            const char* kb_ = (const char*)(Ks + (((size_t)(b * 128 + (TTv) * 2) * 4) << 9)); \
            const char* vb_ = (const char*)(Vs + (((size_t)(b * 64 + (TTv)) * 8) << 9));      \
            _Pragma("unroll")                                                       \
            for (int i_ = 0; i_ < 2; ++i_) {                                        \
                int c_ = wave * 2 + i_;                                             \
                load_lds16(kb_ + c_ * 1024 + (size_t)lane * 16, (char*)ldsK[BUF] + c_ * 1024); \
                load_lds16(vb_ + c_ * 1024 + (size_t)lane * 16, (char*)ldsV[BUF] + c_ * 1024); \
            }                                                                       \
        } while (0)

    STAGE32(tt0, 0);

    for (int tt = tt0; tt < tt1; ++tt) {
        const int cur = (tt - tt0) & 1;
        BAR_VM();                                  // tile tt resident in buf cur
        if (tt + 1 < tt1) STAGE32(tt + 1, cur ^ 1);// DMA flies under compute

        if (tt < ttw) {
            const char* lk = (const char*)ldsK[cur];
            const char* lv = (const char*)ldsV[cur];

            // ---- S = Q K^T (16 rows x 32 keys per m) ----------------------
            f32x4 s2[2][2];
            #pragma unroll
            for (int nsub = 0; nsub < 2; ++nsub) {
                bf16x8 kfr[4];
                #pragma unroll
                for (int ks = 0; ks < 4; ++ks)
                    kfr[ks] = *(const bf16x8*)(lk + ((nsub * 4 + ks) << 10) + lane * 16);
                #pragma unroll
                for (int m = 0; m < 2; ++m) {
                    f32x4 a2 = {0.f, 0.f, 0.f, 0.f};
                    #pragma unroll
                    for (int ks = 0; ks < 4; ++ks)
                        a2 = __builtin_amdgcn_mfma_f32_16x16x32_bf16(qf[m][ks], kfr[ks], a2, 0, 0, 0);
                    s2[m][nsub] = a2;
                }
            }

            const int k0 = tt * 32;
            // ---- mask + exp2 + lane-local l + P write ---------------------
            #pragma unroll
            for (int m = 0; m < 2; ++m) {
                const int qr0m = qw + m * 16;
                if (k0 + 31 > qr0m) {
                    #pragma unroll
                    for (int nsub = 0; nsub < 2; ++nsub) {
                        int key = k0 + nsub * 16 + l16;
                        #pragma unroll
                        for (int r = 0; r < 4; ++r) {
                            int rowq = qr0m + quad * 4 + r;
                            if (key > rowq) s2[m][nsub][r] = -3e38f;
                        }
                    }
                }
                #pragma unroll
                for (int nsub = 0; nsub < 2; ++nsub) {
                    #pragma unroll
                    for (int r = 0; r < 4; ++r) {
                        float p = __builtin_amdgcn_exp2f(s2[m][nsub][r] - EXP_BIAS);
                        l_r[m][r] += p;
                        myP[(m * 16 + quad * 4 + r) * S32 + nsub * 16 + l16] = (__bf16)p;
                    }
                }
            }
            asm volatile("s_waitcnt lgkmcnt(0)" ::: "memory");

            // ---- P: C-layout -> A-layout (one b128 per m) -----------------
            bf16x8 pf[2];
            #pragma unroll
            for (int m = 0; m < 2; ++m)
                pf[m] = *(const bf16x8*)((const char*)myP + (size_t)(m * 16 + l16) * (S32 * 2) + quad * 16);

            // ---- O += P V (k = 32) ----------------------------------------
            #pragma unroll
            for (int h8 = 0; h8 < 8; ++h8) {
                bf16x8 v0 = *(const bf16x8*)(lv + (h8 << 10) + lane * 16);
                #pragma unroll
                for (int m = 0; m < 2; ++m)
                    o[m][h8] = __builtin_amdgcn_mfma_f32_16x16x32_bf16(pf[m], v0, o[m][h8], 0, 0, 0);
            }
        }
        BAR_LGKM();    // all waves' LDS reads of buf cur complete before reuse
    }

    // l reduction across the 16-lane row group
    #pragma unroll
    for (int m = 0; m < 2; ++m)
        #pragma unroll
        for (int r = 0; r < 4; ++r)
            #pragma unroll
            for (int j = 1; j <= 8; j <<= 1)
                l_r[m][r] += __shfl_xor(l_r[m][r], j, 64);

    if (dwrite) {
        #pragma unroll
        for (int m = 0; m < 2; ++m) {
            float inv[4];
            #pragma unroll
            for (int r = 0; r < 4; ++r) inv[r] = 1.0f / l_r[m][r];
            #pragma unroll
            for (int h8 = 0; h8 < 8; ++h8)
                #pragma unroll
                for (int r = 0; r < 4; ++r)
                    outp[(size_t)(b * TT + qw + m * 16 + quad * 4 + r) * HH + h8 * 16 + l16] = o[m][h8][r] * inv[r];
        }
    } else {
        char* slot = po + (size_t)(b * SPB + s) * SLOT_BYTES;
        __bf16* slot_o = (__bf16*)slot;
        float*  slot_l = (float*)(slot + SLOT_L_OFF);
        #pragma unroll
        for (int m = 0; m < 2; ++m) {
            #pragma unroll
            for (int h8 = 0; h8 < 8; ++h8)
                #pragma unroll
                for (int r = 0; r < 4; ++r)
                    slot_o[(size_t)(wave * 32 + m * 16 + quad * 4 + r) * 128 + h8 * 16 + l16] = (__bf16)o[m][h8][r];
            if (l16 == 0) {
                #pragma unroll
                for (int r = 0; r < 4; ++r)
                    slot_l[wave * 32 + m * 16 + quad * 4 + r] = l_r[m][r];
            }
        }
    }
}

// ---------------------------------------------------------------------------
// Reduce: sum bf16 partial o + fp32 l over segments, normalize.
// ---------------------------------------------------------------------------
__global__ __launch_bounds__(256) void reduce_kernel(
    const char* __restrict__ po, float* __restrict__ outp, int G, int SPB)
{
    __shared__ float lsum[32];
    const int qt  = blockIdx.x >> 2;
    const int qtr = blockIdx.x & 3;
    const int b   = blockIdx.y;
    const int tid = threadIdx.x;

    const int segs = (2 * (qt + 1) + G - 1) / G;
    if (segs == 1) return;

    int acc = 0;
    for (int qq = 0; qq < qt; ++qq) acc += (2 * (qq + 1) + G - 1) / G;
    const char* base = po + (size_t)(b * SPB + acc) * SLOT_BYTES;
    const int r0 = qtr * 32;

    if (tid < 32) {
        float v = 0.f;
        for (int sg = 0; sg < segs; ++sg)
            v += ((const float*)(base + (size_t)sg * SLOT_BYTES + SLOT_L_OFF))[r0 + tid];
        lsum[tid] = v;
    }
    __syncthreads();

    const int rsub = tid >> 4;
    const int cg   = tid & 15;
    float a[2][8];
    #pragma unroll
    for (int p = 0; p < 2; ++p)
        #pragma unroll
        for (int j = 0; j < 8; ++j) a[p][j] = 0.f;

    for (int sg = 0; sg < segs; ++sg) {
        const char* sb = base + (size_t)sg * SLOT_BYTES;
        #pragma unroll
        for (int p = 0; p < 2; ++p) {
            int row = r0 + rsub + p * 16;
            union { uint4 u; __bf16 h[8]; } v;
            v.u = *(const uint4*)(sb + ((size_t)row * 128 + cg * 8) * 2);
            #pragma unroll
            for (int j = 0; j < 8; ++j) a[p][j] += (float)v.h[j];
        }
    }

    #pragma unroll
    for (int p = 0; p < 2; ++p) {
        int row = r0 + rsub + p * 16;
        float inv = 1.0f / lsum[rsub + p * 16];
        float* op = outp + (size_t)(b * TT + qt * 128 + row) * HH + cg * 8;
        float4 o0 = {a[p][0] * inv, a[p][1] * inv, a[p][2] * inv, a[p][3] * inv};
        float4 o1 = {a[p][4] * inv, a[p][5] * inv, a[p][6] * inv, a[p][7] * inv};
        *(float4*)op = o0;
        *(float4*)(op + 4) = o1;
    }
}

extern "C" void kernel_launch(void* const* d_in, const int* in_sizes, int n_in,
                              void* d_out, int out_size, void* d_ws, size_t ws_size,
                              hipStream_t stream)
{
    const float* x  = (const float*)d_in[0];
    const float* Wq = (const float*)d_in[1];
    const float* Wk = (const float*)d_in[2];
    const float* Wv = (const float*)d_in[3];
    __bf16* ws = (__bf16*)d_ws;
    float* out = (float*)d_out;
    char* po   = (char*)d_ws + PARTIAL_OFF_BYTES;

    int G = 0, SPB = 0, direct = 1;
    const int cand[3] = {6, 8, 16};
    for (int ci = 0; ci < 3; ++ci) {
        int g = cand[ci], spb = 0;
        for (int q = 0; q < NQT128; ++q) spb += (2 * (q + 1) + g - 1) / g;
        size_t need = PARTIAL_OFF_BYTES + (size_t)spb * BB * SLOT_BYTES;
        if (need <= ws_size) { G = g; SPB = spb; direct = 0; break; }
    }
    if (direct) { G = 2 * NQT128; SPB = NQT128; }

    wcvt_kernel<<<24, 256, 0, stream>>>(Wq, Wk, Wv, ws + WBF_OFF);
    proj_kernel<<<512, 256, 0, stream>>>(x, ws);
    attn_kernel<<<SPB * 16, 256, 0, stream>>>(ws, po, out, G, SPB, direct);
    if (!direct) {
        dim3 rgrid(NQT128 * 4, BB);
        reduce_kernel<<<rgrid, 256, 0, stream>>>(po, out, G, SPB);
    }
}